// Round 9
// baseline (302.730 us; speedup 1.0000x reference)
//
#include <hip/hip_runtime.h>
#include <math.h>

#define N_NODES 50000
#define N_EDGES 800000
#define IN_DIM 128
#define OUT_DIM 16
#define N_HEADS 4
#define HID 64            // N_HEADS*OUT_DIM
#define AW_COLS 33        // 2*OUT_DIM+1
#define NBLK ((N_NODES + 255) / 256)   // 196

// h = nodes @ W.T + b (fp64 accumulate, SAME k-order as prior rounds) fused with
// alphas epilogue. Block = 256 = 4 waves; wave = 1 node, lane = output element.
// sW uses a per-row quad rotation so ds_read_b128 spreads bank-quads.
// NOTE (R7/R8 post-mortem): v_mfma_f64_16x16x4_f64 rewrites produced a
// deterministic wrong h (identical absmax across two different stagings) —
// the f64 MFMA lane mapping differs from the f32-verified convention. Do not
// re-attempt without a hardware layout probe.
__global__ __launch_bounds__(256) void gemm_h(const float* __restrict__ nodes,
                                              const float* __restrict__ W,
                                              const float* __restrict__ b,
                                              const float* __restrict__ attn_W,
                                              float* __restrict__ h,
                                              double* __restrict__ a_src,
                                              double* __restrict__ a_dst) {
    __shared__ float sW[HID * IN_DIM];     // rotated-quad layout
    __shared__ float sN[4 * IN_DIM];
    int t = threadIdx.x;
    for (int i4 = t; i4 < HID * IN_DIM / 4; i4 += 256) {
        int o = i4 >> 5, kq = i4 & 31;
        float4 v = ((const float4*)W)[i4];
        *(float4*)&sW[o * IN_DIM + (((kq + o) & 31) << 2)] = v;
    }
    int node0 = blockIdx.x * 4;
    for (int i4 = t; i4 < 4 * IN_DIM / 4; i4 += 256) {
        int ln = i4 >> 5;
        int n = node0 + ln;
        float4 v = (n < N_NODES) ? ((const float4*)nodes)[(long long)n * (IN_DIM / 4) + (i4 & 31)]
                                 : make_float4(0.f, 0.f, 0.f, 0.f);
        *(float4*)&sN[i4 << 2] = v;
    }
    __syncthreads();
    int ln = t >> 6, o = t & 63;
    int n = node0 + ln;
    if (n >= N_NODES) return;
    double acc = (double)b[o];
    const float* wrow = &sW[o * IN_DIM];
    const float* nrow = &sN[ln * IN_DIM];
    #pragma unroll 8
    for (int kq = 0; kq < 32; ++kq) {
        float4 nv = *(const float4*)&nrow[kq << 2];                  // broadcast (same addr)
        float4 wv = *(const float4*)&wrow[((kq + o) & 31) << 2];     // rotated, spread banks
        acc += (double)wv.x * (double)nv.x;
        acc += (double)wv.y * (double)nv.y;
        acc += (double)wv.z * (double)nv.z;
        acc += (double)wv.w * (double)nv.w;
    }
    float hf = (float)acc;
    h[(long long)n * HID + o] = hf;
    // alphas epilogue from the ROUNDED f32 h (matches reference semantics)
    int hd = o >> 4, d = o & 15;
    double c0 = (double)hf * (double)attn_W[hd * AW_COLS + d];
    double c1 = (double)hf * (double)attn_W[hd * AW_COLS + OUT_DIM + d];
    #pragma unroll
    for (int k = 1; k <= 8; k <<= 1) {
        c0 += __shfl_xor(c0, k, 64);
        c1 += __shfl_xor(c1, k, 64);
    }
    if (d == 0) {
        a_src[n * N_HEADS + hd] = c0;
        a_dst[n * N_HEADS + hd] = c1;
    }
}

// Receiver histogram + block-reduced double sum of edges[sender] -> Ssum.
__global__ __launch_bounds__(256) void hist(const int* __restrict__ senders,
                                            const int* __restrict__ receivers,
                                            const float* __restrict__ edges,
                                            int* __restrict__ counts,
                                            double* __restrict__ Ssum) {
    __shared__ double red[256];
    int t = threadIdx.x;
    int e = blockIdx.x * 256 + t;
    double sp = 0.0;
    if (e < N_EDGES) {
        atomicAdd(&counts[receivers[e]], 1);
        sp = (double)edges[senders[e]];
    }
    red[t] = sp;
    __syncthreads();
    for (int off = 128; off > 0; off >>= 1) {
        if (t < off) red[t] += red[t + off];
        __syncthreads();
    }
    if (t == 0) atomicAdd(Ssum, red[0]);
}

// ---- 3-phase multi-block exclusive scan of counts -> offsets/cursor ----
__global__ __launch_bounds__(256) void partial_sums(const int* __restrict__ counts,
                                                    int* __restrict__ partials) {
    __shared__ int red[256];
    int t = threadIdx.x;
    int i = blockIdx.x * 256 + t;
    red[t] = (i < N_NODES) ? counts[i] : 0;
    __syncthreads();
    for (int off = 128; off > 0; off >>= 1) {
        if (t < off) red[t] += red[t + off];
        __syncthreads();
    }
    if (t == 0) partials[blockIdx.x] = red[0];
}

__global__ __launch_bounds__(256) void scan_partials(int* __restrict__ partials) {
    __shared__ int s[256];
    int t = threadIdx.x;
    int v = (t < NBLK) ? partials[t] : 0;
    s[t] = v;
    __syncthreads();
    for (int off = 1; off < 256; off <<= 1) {
        int u = (t >= off) ? s[t - off] : 0;
        __syncthreads();
        s[t] += u;
        __syncthreads();
    }
    if (t < NBLK) partials[t] = s[t] - v;   // exclusive block offsets
}

__global__ __launch_bounds__(256) void scan_final(const int* __restrict__ counts,
                                                  const int* __restrict__ partials,
                                                  int* __restrict__ offsets,
                                                  int* __restrict__ cursor) {
    __shared__ int s[256];
    int t = threadIdx.x;
    int i = blockIdx.x * 256 + t;
    int c = (i < N_NODES) ? counts[i] : 0;
    s[t] = c;
    __syncthreads();
    for (int off = 1; off < 256; off <<= 1) {
        int u = (t >= off) ? s[t - off] : 0;
        __syncthreads();
        s[t] += u;
        __syncthreads();
    }
    if (i < N_NODES) {
        int pos = partials[blockIdx.x] + s[t] - c;   // exclusive prefix
        offsets[i] = pos;
        cursor[i] = pos;
    }
    if (i == 0) offsets[N_NODES] = N_EDGES;
}

// Scatter sender ids into receiver-sorted order.
__global__ __launch_bounds__(256) void fill_srt(const int* __restrict__ senders,
                                                const int* __restrict__ receivers,
                                                int* __restrict__ cursor,
                                                int* __restrict__ srt_sender) {
    int e = blockIdx.x * 256 + threadIdx.x;
    if (e >= N_EDGES) return;
    int pos = atomicAdd(&cursor[receivers[e]], 1);
    srt_sender[pos] = senders[e];
}

// One wave per node. Lane = (head hd=lane>>4, slot q=lane&15); lane evaluates
// edges q+16j for ITS head only. Segmented 16-lane reductions for max/den.
// Near-one-hot softmax -> ballot-compressed accumulate loop.
__global__ __launch_bounds__(256) void node_fused(
    const float* __restrict__ h, const double* __restrict__ a_src,
    const double* __restrict__ a_dst, const float* __restrict__ edges,
    const int* __restrict__ srt_sender, const int* __restrict__ offsets,
    const float* __restrict__ attn_W, const float* __restrict__ attn_b,
    const double* __restrict__ Ssum, float* __restrict__ out) {
    int node = blockIdx.x * 4 + (threadIdx.x >> 6);
    int lane = threadIdx.x & 63;
    if (node >= N_NODES) return;
    int hd = lane >> 4, q = lane & 15;
    int start = offsets[node], end = offsets[node + 1];
    long long obase = (long long)node * HID + lane;
    if (start >= end) { out[obase] = 0.f; return; }

    double S = 4.0 * Ssum[0];                       // sent_e tiled over heads
    double w    = (double)attn_W[hd * AW_COLS + 2 * OUT_DIM];
    double bb   = (double)attn_b[hd];
    double adst = a_dst[node * N_HEADS + hd];
    float m_run = -INFINITY;
    float den = 0.f, acc = 0.f;

    for (int cbase = start; cbase < end; cbase += 64) {
        int cd = end - cbase; if (cd > 64) cd = 64;
        float y[4], ev[4];
        #pragma unroll
        for (int j = 0; j < 4; ++j) {
            int ei = q + 16 * j;
            y[j] = -INFINITY;
            if (ei < cd) {
                int s = srt_sender[cbase + ei];
                double se = (double)edges[s];
                double as = a_src[(long long)s * N_HEADS + hd];
                double yy = as + adst + se * w + bb;
                yy = yy > 0.0 ? yy : 0.01 * yy;     // leaky (fp64, then round)
                y[j] = (float)yy;
            }
        }
        // per-head (16-lane segment) chunk max
        float mv = fmaxf(fmaxf(y[0], y[1]), fmaxf(y[2], y[3]));
        #pragma unroll
        for (int k = 1; k <= 8; k <<= 1)
            mv = fmaxf(mv, __shfl_xor(mv, k, 64));
        float mn = fmaxf(m_run, mv);
        float sc = (m_run == -INFINITY) ? 0.f
                 : __expf((float)(S * ((double)m_run - (double)mn)));
        den *= sc; acc *= sc; m_run = mn;
        // ev per slot (fp64 arg, fp32 exp) + segmented den sum
        float dsum = 0.f;
        #pragma unroll
        for (int j = 0; j < 4; ++j) {
            ev[j] = (y[j] == -INFINITY) ? 0.f
                  : __expf((float)(S * ((double)y[j] - (double)m_run)));
            dsum += ev[j];
        }
        #pragma unroll
        for (int k = 1; k <= 8; k <<= 1)
            dsum += __shfl_xor(dsum, k, 64);
        den += dsum;
        // accumulate only surviving edges (exact skip of ev==0)
        #pragma unroll
        for (int j = 0; j < 4; ++j) {
            unsigned long long mk = __ballot(ev[j] != 0.f);
            unsigned um = (unsigned)((mk | (mk >> 16) | (mk >> 32) | (mk >> 48)) & 0xFFFFull);
            while (um) {
                int qq = __builtin_ctz(um);
                um &= um - 1;
                float evv = __shfl(ev[j], (lane & 48) | qq, 64);  // own head's ev
                int sj = srt_sender[cbase + 16 * j + qq];         // uniform -> scalar
                if (evv != 0.f)
                    acc = fmaf(evv, h[(long long)sj * HID + lane], acc);
            }
        }
    }
    float r = (den > 0.f) ? acc / den : 0.f;
    out[obase] = r > 0.f ? r : 0.01f * r;
}

static inline char* ws_take(char*& p, size_t bytes) {
    char* cur = p;
    p += (bytes + 255) & ~(size_t)255;   // keep every buffer 256B-aligned
    return cur;
}

extern "C" void kernel_launch(void* const* d_in, const int* in_sizes, int n_in,
                              void* d_out, int out_size, void* d_ws, size_t ws_size,
                              hipStream_t stream) {
    const float* nodes     = (const float*)d_in[0];
    const float* edges     = (const float*)d_in[1];
    const int*   senders   = (const int*)d_in[2];
    const int*   receivers = (const int*)d_in[3];
    const float* W         = (const float*)d_in[4];
    const float* b         = (const float*)d_in[5];
    const float* attn_W    = (const float*)d_in[6];
    const float* attn_b    = (const float*)d_in[7];
    float* out = (float*)d_out;

    char* p = (char*)d_ws;
    float*  h          = (float*)ws_take(p, sizeof(float) * N_NODES * HID);
    double* a_src      = (double*)ws_take(p, sizeof(double) * N_NODES * N_HEADS);
    double* a_dst      = (double*)ws_take(p, sizeof(double) * N_NODES * N_HEADS);
    int*    counts     = (int*)ws_take(p, sizeof(int) * N_NODES);
    int*    offsets    = (int*)ws_take(p, sizeof(int) * (N_NODES + 1));
    int*    cursor     = (int*)ws_take(p, sizeof(int) * N_NODES);
    int*    partials   = (int*)ws_take(p, sizeof(int) * NBLK);
    int*    srt_sender = (int*)ws_take(p, sizeof(int) * (size_t)N_EDGES);
    double* Ssum       = (double*)ws_take(p, sizeof(double));

    hipMemsetAsync(counts, 0, sizeof(int) * N_NODES, stream);
    hipMemsetAsync(Ssum, 0, sizeof(double), stream);

    gemm_h<<<(N_NODES + 3) / 4, 256, 0, stream>>>(nodes, W, b, attn_W, h, a_src, a_dst);
    hist<<<(N_EDGES + 255) / 256, 256, 0, stream>>>(senders, receivers, edges, counts, Ssum);
    partial_sums<<<NBLK, 256, 0, stream>>>(counts, partials);
    scan_partials<<<1, 256, 0, stream>>>(partials);
    scan_final<<<NBLK, 256, 0, stream>>>(counts, partials, offsets, cursor);
    fill_srt<<<(N_EDGES + 255) / 256, 256, 0, stream>>>(senders, receivers, cursor, srt_sender);
    node_fused<<<(N_NODES + 3) / 4, 256, 0, stream>>>(
        h, a_src, a_dst, edges, srt_sender, offsets, attn_W, attn_b, Ssum, out);
}